// Round 1
// baseline (256.158 us; speedup 1.0000x reference)
//
#include <hip/hip_runtime.h>
#include <stdint.h>

// Problem dims (fixed): B=2, S=2048, D=1024, H=16, d_head=64
#define SEQ 2048
#define A_SIZE 4194304   // 2*2048*1024 floats (output 'a'), present follows

typedef short short8 __attribute__((ext_vector_type(8)));
typedef float f32x4 __attribute__((ext_vector_type(4)));

#define AS1 __attribute__((address_space(1)))
#define AS3 __attribute__((address_space(3)))

static __device__ __forceinline__ void async16(const void* g, void* l) {
  __builtin_amdgcn_global_load_lds((const AS1 uint32_t*)g, (AS3 uint32_t*)l, 16, 0, 0);
}

static __device__ __forceinline__ unsigned short f2bf(float f) {
  union { float f; uint32_t u; } v; v.f = f;
  uint32_t u = v.u;
  return (unsigned short)((u + 0x7FFFu + ((u >> 16) & 1u)) >> 16);
}

// ---------------- convert x -> bf16 (straight) ----------------
__global__ void k_cvt(const float* __restrict__ in, unsigned short* __restrict__ out, int n4) {
  int i = blockIdx.x * blockDim.x + threadIdx.x;
  if (i >= n4) return;
  float4 f = ((const float4*)in)[i];
  ushort4 o;
  o.x = f2bf(f.x); o.y = f2bf(f.y); o.z = f2bf(f.z); o.w = f2bf(f.w);
  ((ushort4*)out)[i] = o;
}

// ------- convert + transpose: in [R][C] f32 -> out [C][R] bf16 -------
__global__ void k_tcvt(const float* __restrict__ in, unsigned short* __restrict__ out,
                       int R, int C) {
  __shared__ unsigned short tile[64][65];
  int c0 = blockIdx.x * 64, r0 = blockIdx.y * 64;
  int tid = threadIdx.x;
  #pragma unroll
  for (int it = 0; it < 16; ++it) {
    int idx = it * 256 + tid;
    int r = idx >> 6, c = idx & 63;
    tile[r][c] = f2bf(in[(size_t)(r0 + r) * C + c0 + c]);
  }
  __syncthreads();
  #pragma unroll
  for (int it = 0; it < 16; ++it) {
    int idx = it * 256 + tid;
    int r = idx >> 6, c = idx & 63;
    out[(size_t)(c0 + r) * R + r0 + c] = tile[c][r];
  }
}

// ---------------- QKV GEMM: C[4096,3072] = A[4096,1024] * BT[3072,1024]^T + bias ----
// m97 structure: 128x128 tile, BK=32, 4 waves, global_load_lds staging.
__global__ __launch_bounds__(256) void k_gemm_qkv(
    const unsigned short* __restrict__ A,
    const unsigned short* __restrict__ BT,
    const float* __restrict__ bias,
    float* __restrict__ outp,          // d_out base; present at +A_SIZE
    unsigned short* __restrict__ q_ws,
    unsigned short* __restrict__ k_ws,
    unsigned short* __restrict__ v_ws) {
  const int K = 1024;
  __shared__ unsigned short Asm[128 * 32];
  __shared__ unsigned short Bsm[128 * 32];
  int tid = threadIdx.x;
  int lane = tid & 63, w = tid >> 6;
  int g = lane >> 4, qi = lane & 15;
  int wr = w >> 1, wc = w & 1;
  int bm = blockIdx.x & 31, bn = blockIdx.x >> 5;
  const unsigned short* Ag = A + (size_t)bm * 128 * K;
  const unsigned short* Bg = BT + (size_t)bn * 128 * K;
  f32x4 acc[4][4] = {};
  for (int kt = 0; kt < K; kt += 32) {
    #pragma unroll
    for (int i = 0; i < 2; ++i) {
      int j = i * 256 + tid;
      async16(Ag + (size_t)(j >> 2) * K + kt + (j & 3) * 8,
              (char*)Asm + (i * 256 + w * 64) * 16);
      async16(Bg + (size_t)(j >> 2) * K + kt + (j & 3) * 8,
              (char*)Bsm + (i * 256 + w * 64) * 16);
    }
    __syncthreads();
    short8 af[4], bf[4];
    #pragma unroll
    for (int mi = 0; mi < 4; ++mi)
      af[mi] = *(const short8*)&Asm[(wr * 64 + mi * 16 + qi) * 32 + g * 8];
    #pragma unroll
    for (int ni = 0; ni < 4; ++ni)
      bf[ni] = *(const short8*)&Bsm[(wc * 64 + ni * 16 + qi) * 32 + g * 8];
    #pragma unroll
    for (int mi = 0; mi < 4; ++mi)
      #pragma unroll
      for (int ni = 0; ni < 4; ++ni)
        acc[mi][ni] = __builtin_amdgcn_mfma_f32_16x16x32_bf16(af[mi], bf[ni], acc[mi][ni], 0, 0, 0);
    __syncthreads();
  }
  // Epilogue: scatter to q/k/v ws (bf16) and present (fp32).
  int m_base = bm * 128 + wr * 64;
  int n_base = bn * 128 + wc * 64;
  #pragma unroll
  for (int ni = 0; ni < 4; ++ni) {
    int n = n_base + ni * 16 + qi;
    float bv = bias[n];
    int which = n >> 10;
    int h = (n & 1023) >> 6, d = n & 63;
    #pragma unroll
    for (int mi = 0; mi < 4; ++mi) {
      #pragma unroll
      for (int r = 0; r < 4; ++r) {
        int m = m_base + mi * 16 + g * 4 + r;
        float val = acc[mi][ni][r] + bv;
        int b = m >> 11, s = m & 2047;
        size_t hsd = (((size_t)(b * 16 + h)) * SEQ + s) * 64 + d;
        if (which == 0) {
          q_ws[hsd] = f2bf(val);
        } else if (which == 1) {
          outp[A_SIZE + (((size_t)(b * 32 + h)) * SEQ + s) * 64 + d] = val;      // present[b][0][h]
          k_ws[hsd] = f2bf(val);
        } else {
          outp[A_SIZE + (((size_t)(b * 32 + 16 + h)) * SEQ + s) * 64 + d] = val; // present[b][1][h]
          v_ws[hsd] = f2bf(val);
        }
      }
    }
  }
}

// ---------------- proj GEMM: out[4096,1024] = A[4096,1024] * BT[1024,1024]^T + bias ----
__global__ __launch_bounds__(256) void k_gemm_proj(
    const unsigned short* __restrict__ A,
    const unsigned short* __restrict__ BT,
    const float* __restrict__ bias,
    float* __restrict__ outp) {
  const int K = 1024;
  __shared__ unsigned short Asm[128 * 32];
  __shared__ unsigned short Bsm[128 * 32];
  int tid = threadIdx.x;
  int lane = tid & 63, w = tid >> 6;
  int g = lane >> 4, qi = lane & 15;
  int wr = w >> 1, wc = w & 1;
  int bm = blockIdx.x & 31, bn = blockIdx.x >> 5;
  const unsigned short* Ag = A + (size_t)bm * 128 * K;
  const unsigned short* Bg = BT + (size_t)bn * 128 * K;
  f32x4 acc[4][4] = {};
  for (int kt = 0; kt < K; kt += 32) {
    #pragma unroll
    for (int i = 0; i < 2; ++i) {
      int j = i * 256 + tid;
      async16(Ag + (size_t)(j >> 2) * K + kt + (j & 3) * 8,
              (char*)Asm + (i * 256 + w * 64) * 16);
      async16(Bg + (size_t)(j >> 2) * K + kt + (j & 3) * 8,
              (char*)Bsm + (i * 256 + w * 64) * 16);
    }
    __syncthreads();
    short8 af[4], bf[4];
    #pragma unroll
    for (int mi = 0; mi < 4; ++mi)
      af[mi] = *(const short8*)&Asm[(wr * 64 + mi * 16 + qi) * 32 + g * 8];
    #pragma unroll
    for (int ni = 0; ni < 4; ++ni)
      bf[ni] = *(const short8*)&Bsm[(wc * 64 + ni * 16 + qi) * 32 + g * 8];
    #pragma unroll
    for (int mi = 0; mi < 4; ++mi)
      #pragma unroll
      for (int ni = 0; ni < 4; ++ni)
        acc[mi][ni] = __builtin_amdgcn_mfma_f32_16x16x32_bf16(af[mi], bf[ni], acc[mi][ni], 0, 0, 0);
    __syncthreads();
  }
  int m_base = bm * 128 + wr * 64;
  int n_base = bn * 128 + wc * 64;
  #pragma unroll
  for (int ni = 0; ni < 4; ++ni) {
    int n = n_base + ni * 16 + qi;
    float bv = bias[n];
    #pragma unroll
    for (int mi = 0; mi < 4; ++mi)
      #pragma unroll
      for (int r = 0; r < 4; ++r) {
        int m = m_base + mi * 16 + g * 4 + r;
        outp[(size_t)m * 1024 + n] = acc[mi][ni][r] + bv;
      }
  }
}

// ---------------- flash attention (causal), bf16 MFMA ----------------
// grid: B*H*(S/64) blocks of 256 threads; each wave owns 16 q-rows.
// Swapped QK^T: S^T = mfma(K_frag, Q_frag) -> row-softmax reduces over regs + lanes^16/^32.
__global__ __launch_bounds__(256) void k_attn(
    const unsigned short* __restrict__ q_ws,
    const unsigned short* __restrict__ k_ws,
    const unsigned short* __restrict__ v_ws,
    unsigned short* __restrict__ a_out) {
  __shared__ unsigned short VT[64 * 40];       // V^T tile [d=64][k=32], stride 40
  __shared__ unsigned short P[4][16 * 40];     // per-wave P [q=16][k=32], stride 40
  const int nqb = SEQ / 64;
  int bh = blockIdx.x / nqb;
  int q0 = (blockIdx.x % nqb) * 64;
  int tid = threadIdx.x, lane = tid & 63, w = tid >> 6;
  int g = lane >> 4, qi = lane & 15;
  int qw = q0 + w * 16;
  int qrow = qw + qi;
  const unsigned short* Qb = q_ws + (size_t)bh * SEQ * 64;
  const unsigned short* Kb = k_ws + (size_t)bh * SEQ * 64;
  const unsigned short* Vb = v_ws + (size_t)bh * SEQ * 64;

  short8 qf0 = *(const short8*)&Qb[(size_t)(qw + qi) * 64 + g * 8];
  short8 qf1 = *(const short8*)&Qb[(size_t)(qw + qi) * 64 + g * 8 + 32];

  f32x4 oacc[4] = {};
  float m_run = -3.0e38f, l_run = 0.f;
  int nkb = (q0 + 64) / 32;

  for (int kb = 0; kb < nkb; ++kb) {
    int k0 = kb * 32;
    __syncthreads();
    {  // cooperative V^T staging (32 keys x 64 d)
      int key = tid >> 3, dc = tid & 7;
      short8 vv = *(const short8*)&Vb[(size_t)(k0 + key) * 64 + dc * 8];
      #pragma unroll
      for (int jj = 0; jj < 8; ++jj) VT[(dc * 8 + jj) * 40 + key] = vv[jj];
    }
    __syncthreads();
    if (k0 > qw + 15) continue;  // wave-uniform causal skip (barriers already passed)

    f32x4 sacc[2];
    #pragma unroll
    for (int st = 0; st < 2; ++st) {
      short8 kf0 = *(const short8*)&Kb[(size_t)(k0 + st * 16 + qi) * 64 + g * 8];
      short8 kf1 = *(const short8*)&Kb[(size_t)(k0 + st * 16 + qi) * 64 + g * 8 + 32];
      f32x4 z = {};
      sacc[st] = __builtin_amdgcn_mfma_f32_16x16x32_bf16(kf0, qf0, z, 0, 0, 0);
      sacc[st] = __builtin_amdgcn_mfma_f32_16x16x32_bf16(kf1, qf1, sacc[st], 0, 0, 0);
    }
    // online softmax over 32 keys (lane holds keys st*16+g*4+r for q=qw+qi)
    float s[8];
    float tmax = -3.0e38f;
    #pragma unroll
    for (int st = 0; st < 2; ++st)
      #pragma unroll
      for (int r = 0; r < 4; ++r) {
        int key = k0 + st * 16 + g * 4 + r;
        float v = sacc[st][r] * 0.125f;
        v = (key <= qrow) ? v : -3.0e38f;
        s[st * 4 + r] = v;
        tmax = fmaxf(tmax, v);
      }
    tmax = fmaxf(tmax, __shfl_xor(tmax, 16, 64));
    tmax = fmaxf(tmax, __shfl_xor(tmax, 32, 64));
    float m_new = fmaxf(m_run, tmax);
    float alpha = __expf(m_run - m_new);
    float psum = 0.f;
    unsigned short pb[8];
    #pragma unroll
    for (int i = 0; i < 8; ++i) {
      float p = (s[i] > -1.0e37f) ? __expf(s[i] - m_new) : 0.f;
      psum += p;
      pb[i] = f2bf(p);
    }
    psum += __shfl_xor(psum, 16, 64);
    psum += __shfl_xor(psum, 32, 64);
    l_run = l_run * alpha + psum;
    m_run = m_new;
    // P -> per-wave LDS [q][k] (pack reg pairs into b32 writes)
    unsigned short* Pw = &P[w][0];
    #pragma unroll
    for (int st = 0; st < 2; ++st) {
      uint32_t lo = (uint32_t)pb[st * 4 + 0] | ((uint32_t)pb[st * 4 + 1] << 16);
      uint32_t hi = (uint32_t)pb[st * 4 + 2] | ((uint32_t)pb[st * 4 + 3] << 16);
      *(uint32_t*)&Pw[qi * 40 + st * 16 + g * 4] = lo;
      *(uint32_t*)&Pw[qi * 40 + st * 16 + g * 4 + 2] = hi;
    }
    short8 pa = *(const short8*)&Pw[qi * 40 + g * 8];
    // redistribute alpha to output-row layout (row q = qw + g*4 + r)
    float ao[4];
    #pragma unroll
    for (int r = 0; r < 4; ++r) ao[r] = __shfl(alpha, g * 4 + r, 64);
    #pragma unroll
    for (int dt = 0; dt < 4; ++dt) {
      short8 vf = *(const short8*)&VT[(dt * 16 + qi) * 40 + g * 8];
      f32x4 t = oacc[dt];
      #pragma unroll
      for (int r = 0; r < 4; ++r) t[r] *= ao[r];
      oacc[dt] = __builtin_amdgcn_mfma_f32_16x16x32_bf16(pa, vf, t, 0, 0, 0);
    }
  }
  float lo_[4];
  #pragma unroll
  for (int r = 0; r < 4; ++r) lo_[r] = __shfl(l_run, g * 4 + r, 64);
  int b = bh >> 4, h = bh & 15;
  #pragma unroll
  for (int dt = 0; dt < 4; ++dt)
    #pragma unroll
    for (int r = 0; r < 4; ++r) {
      int srow = qw + g * 4 + r;
      a_out[((size_t)b * SEQ + srow) * 1024 + h * 64 + dt * 16 + qi] =
          f2bf(oacc[dt][r] / lo_[r]);
    }
}

// ---------------- launch ----------------
extern "C" void kernel_launch(void* const* d_in, const int* in_sizes, int n_in,
                              void* d_out, int out_size, void* d_ws, size_t ws_size,
                              hipStream_t stream) {
  const float* x      = (const float*)d_in[0];
  const float* w_attn = (const float*)d_in[1];
  const float* b_attn = (const float*)d_in[2];
  const float* w_proj = (const float*)d_in[3];
  const float* b_proj = (const float*)d_in[4];
  float* out = (float*)d_out;
  char* ws = (char*)d_ws;
  // ws layout (48 MB total)
  unsigned short* x_bf = (unsigned short*)(ws);               //  8 MB
  unsigned short* waT  = (unsigned short*)(ws + 8388608);     //  6 MB
  unsigned short* wpT  = (unsigned short*)(ws + 14680064);    //  2 MB
  unsigned short* q_ws = (unsigned short*)(ws + 16777216);    //  8 MB
  unsigned short* k_ws = (unsigned short*)(ws + 25165824);    //  8 MB
  unsigned short* v_ws = (unsigned short*)(ws + 33554432);    //  8 MB
  unsigned short* a_ws = (unsigned short*)(ws + 41943040);    //  8 MB

  hipLaunchKernelGGL(k_cvt, dim3(4096), dim3(256), 0, stream, x, x_bf, 4194304 / 4);
  hipLaunchKernelGGL(k_tcvt, dim3(48, 16), dim3(256), 0, stream, w_attn, waT, 1024, 3072);
  hipLaunchKernelGGL(k_tcvt, dim3(16, 16), dim3(256), 0, stream, w_proj, wpT, 1024, 1024);
  hipLaunchKernelGGL(k_gemm_qkv, dim3(768), dim3(256), 0, stream,
                     x_bf, waT, b_attn, out, q_ws, k_ws, v_ws);
  hipLaunchKernelGGL(k_attn, dim3(1024), dim3(256), 0, stream, q_ws, k_ws, v_ws, a_ws);
  hipLaunchKernelGGL(k_gemm_proj, dim3(256), dim3(256), 0, stream, a_ws, wpT, b_proj, out);
}

// Round 2
// 220.443 us; speedup vs baseline: 1.1620x; 1.1620x over previous
//
#include <hip/hip_runtime.h>
#include <stdint.h>

// Problem dims (fixed): B=2, S=2048, D=1024, H=16, d_head=64
#define SEQ 2048
#define A_SIZE 4194304   // 2*2048*1024 floats (output 'a'), present follows

typedef short short8 __attribute__((ext_vector_type(8)));
typedef float f32x4 __attribute__((ext_vector_type(4)));

#define AS1 __attribute__((address_space(1)))
#define AS3 __attribute__((address_space(3)))

static __device__ __forceinline__ void async16(const void* g, void* l) {
  __builtin_amdgcn_global_load_lds((const AS1 uint32_t*)g, (AS3 uint32_t*)l, 16, 0, 0);
}

static __device__ __forceinline__ unsigned short f2bf(float f) {
  union { float f; uint32_t u; } v; v.f = f;
  uint32_t u = v.u;
  return (unsigned short)((u + 0x7FFFu + ((u >> 16) & 1u)) >> 16);
}

// ---------------- convert x -> bf16 (straight) ----------------
__global__ void k_cvt(const float* __restrict__ in, unsigned short* __restrict__ out, int n4) {
  int i = blockIdx.x * blockDim.x + threadIdx.x;
  if (i >= n4) return;
  float4 f = ((const float4*)in)[i];
  ushort4 o;
  o.x = f2bf(f.x); o.y = f2bf(f.y); o.z = f2bf(f.z); o.w = f2bf(f.w);
  ((ushort4*)out)[i] = o;
}

// ------- convert + transpose: in [R][C] f32 -> out [C][R] bf16 -------
__global__ void k_tcvt(const float* __restrict__ in, unsigned short* __restrict__ out,
                       int R, int C) {
  __shared__ unsigned short tile[64][65];
  int c0 = blockIdx.x * 64, r0 = blockIdx.y * 64;
  int tid = threadIdx.x;
  #pragma unroll
  for (int it = 0; it < 16; ++it) {
    int idx = it * 256 + tid;
    int r = idx >> 6, c = idx & 63;
    tile[r][c] = f2bf(in[(size_t)(r0 + r) * C + c0 + c]);
  }
  __syncthreads();
  #pragma unroll
  for (int it = 0; it < 16; ++it) {
    int idx = it * 256 + tid;
    int r = idx >> 6, c = idx & 63;
    out[(size_t)(c0 + r) * R + r0 + c] = tile[c][r];
  }
}

// ---------------- QKV GEMM: C[4096,3072] = A[4096,1024] * BT[3072,1024]^T + bias ----
__global__ __launch_bounds__(256) void k_gemm_qkv(
    const unsigned short* __restrict__ A,
    const unsigned short* __restrict__ BT,
    const float* __restrict__ bias,
    float* __restrict__ outp,          // d_out base; present at +A_SIZE
    unsigned short* __restrict__ q_ws,
    unsigned short* __restrict__ k_ws,
    unsigned short* __restrict__ vT_ws) {
  const int K = 1024;
  __shared__ unsigned short Asm[128 * 32];
  __shared__ unsigned short Bsm[128 * 32];
  int tid = threadIdx.x;
  int lane = tid & 63, w = tid >> 6;
  int g = lane >> 4, qi = lane & 15;
  int wr = w >> 1, wc = w & 1;
  int bm = blockIdx.x & 31, bn = blockIdx.x >> 5;
  const unsigned short* Ag = A + (size_t)bm * 128 * K;
  const unsigned short* Bg = BT + (size_t)bn * 128 * K;
  f32x4 acc[4][4] = {};
  for (int kt = 0; kt < K; kt += 32) {
    #pragma unroll
    for (int i = 0; i < 2; ++i) {
      int j = i * 256 + tid;
      async16(Ag + (size_t)(j >> 2) * K + kt + (j & 3) * 8,
              (char*)Asm + (i * 256 + w * 64) * 16);
      async16(Bg + (size_t)(j >> 2) * K + kt + (j & 3) * 8,
              (char*)Bsm + (i * 256 + w * 64) * 16);
    }
    __syncthreads();
    short8 af[4], bf[4];
    #pragma unroll
    for (int mi = 0; mi < 4; ++mi)
      af[mi] = *(const short8*)&Asm[(wr * 64 + mi * 16 + qi) * 32 + g * 8];
    #pragma unroll
    for (int ni = 0; ni < 4; ++ni)
      bf[ni] = *(const short8*)&Bsm[(wc * 64 + ni * 16 + qi) * 32 + g * 8];
    #pragma unroll
    for (int mi = 0; mi < 4; ++mi)
      #pragma unroll
      for (int ni = 0; ni < 4; ++ni)
        acc[mi][ni] = __builtin_amdgcn_mfma_f32_16x16x32_bf16(af[mi], bf[ni], acc[mi][ni], 0, 0, 0);
    __syncthreads();
  }
  // Epilogue: scatter to q/k (bf16, [B,H,S,d]), v transposed ([B,H,d,S]), present (fp32).
  int m_base = bm * 128 + wr * 64;
  int n_base = bn * 128 + wc * 64;
  #pragma unroll
  for (int ni = 0; ni < 4; ++ni) {
    int n = n_base + ni * 16 + qi;
    float bv = bias[n];
    int which = n >> 10;
    int h = (n & 1023) >> 6, d = n & 63;
    #pragma unroll
    for (int mi = 0; mi < 4; ++mi) {
      #pragma unroll
      for (int r = 0; r < 4; ++r) {
        int m = m_base + mi * 16 + g * 4 + r;
        float val = acc[mi][ni][r] + bv;
        int b = m >> 11, s = m & 2047;
        if (which == 0) {
          q_ws[(((size_t)(b * 16 + h)) * SEQ + s) * 64 + d] = f2bf(val);
        } else if (which == 1) {
          outp[A_SIZE + (((size_t)(b * 32 + h)) * SEQ + s) * 64 + d] = val;      // present[b][0][h]
          k_ws[(((size_t)(b * 16 + h)) * SEQ + s) * 64 + d] = f2bf(val);
        } else {
          outp[A_SIZE + (((size_t)(b * 32 + 16 + h)) * SEQ + s) * 64 + d] = val; // present[b][1][h]
          vT_ws[(((size_t)(b * 16 + h)) * 64 + d) * SEQ + s] = f2bf(val);        // V^T
        }
      }
    }
  }
}

// ---------------- proj GEMM: out[4096,1024] = A[4096,1024] * BT[1024,1024]^T + bias ----
__global__ __launch_bounds__(256) void k_gemm_proj(
    const unsigned short* __restrict__ A,
    const unsigned short* __restrict__ BT,
    const float* __restrict__ bias,
    float* __restrict__ outp) {
  const int K = 1024;
  __shared__ unsigned short Asm[128 * 32];
  __shared__ unsigned short Bsm[128 * 32];
  int tid = threadIdx.x;
  int lane = tid & 63, w = tid >> 6;
  int g = lane >> 4, qi = lane & 15;
  int wr = w >> 1, wc = w & 1;
  int bm = blockIdx.x & 31, bn = blockIdx.x >> 5;
  const unsigned short* Ag = A + (size_t)bm * 128 * K;
  const unsigned short* Bg = BT + (size_t)bn * 128 * K;
  f32x4 acc[4][4] = {};
  for (int kt = 0; kt < K; kt += 32) {
    #pragma unroll
    for (int i = 0; i < 2; ++i) {
      int j = i * 256 + tid;
      async16(Ag + (size_t)(j >> 2) * K + kt + (j & 3) * 8,
              (char*)Asm + (i * 256 + w * 64) * 16);
      async16(Bg + (size_t)(j >> 2) * K + kt + (j & 3) * 8,
              (char*)Bsm + (i * 256 + w * 64) * 16);
    }
    __syncthreads();
    short8 af[4], bf[4];
    #pragma unroll
    for (int mi = 0; mi < 4; ++mi)
      af[mi] = *(const short8*)&Asm[(wr * 64 + mi * 16 + qi) * 32 + g * 8];
    #pragma unroll
    for (int ni = 0; ni < 4; ++ni)
      bf[ni] = *(const short8*)&Bsm[(wc * 64 + ni * 16 + qi) * 32 + g * 8];
    #pragma unroll
    for (int mi = 0; mi < 4; ++mi)
      #pragma unroll
      for (int ni = 0; ni < 4; ++ni)
        acc[mi][ni] = __builtin_amdgcn_mfma_f32_16x16x32_bf16(af[mi], bf[ni], acc[mi][ni], 0, 0, 0);
    __syncthreads();
  }
  int m_base = bm * 128 + wr * 64;
  int n_base = bn * 128 + wc * 64;
  #pragma unroll
  for (int ni = 0; ni < 4; ++ni) {
    int n = n_base + ni * 16 + qi;
    float bv = bias[n];
    #pragma unroll
    for (int mi = 0; mi < 4; ++mi)
      #pragma unroll
      for (int r = 0; r < 4; ++r) {
        int m = m_base + mi * 16 + g * 4 + r;
        outp[(size_t)m * 1024 + n] = acc[mi][ni][r] + bv;
      }
  }
}

// ---------------- flash attention (causal), barrier-free ----------------
// grid: (S/64) * B*H blocks of 256 threads; 4 independent waves x 16 q-rows.
// Swapped QK^T (S^T = mfma(K,Q)); PV computes O^T = mfma(V^T, P^T) so alpha/l
// are per-lane (no shuffles) and output stores vectorize. K and V^T read
// directly from global (L2-resident, 256KB/head) — no barriers anywhere.
__global__ __launch_bounds__(256) void k_attn(
    const unsigned short* __restrict__ q_ws,
    const unsigned short* __restrict__ k_ws,
    const unsigned short* __restrict__ vT_ws,
    unsigned short* __restrict__ a_out) {
  __shared__ unsigned short P[4][16 * 36];   // per-wave P [q=16][k=32], stride 36
  const int nqb = SEQ / 64;   // 32
  const int nbh = 32;         // B*H
  int qidx = blockIdx.x / nbh;
  int bh = blockIdx.x % nbh;
  int q0 = (nqb - 1 - qidx) * 64;           // heaviest causal blocks launch first
  int tid = threadIdx.x, lane = tid & 63, w = tid >> 6;
  int g = lane >> 4, qi = lane & 15;
  int qw = q0 + w * 16;
  int qrow = qw + qi;
  const unsigned short* Qb = q_ws + (size_t)bh * SEQ * 64;
  const unsigned short* Kb = k_ws + (size_t)bh * SEQ * 64;
  const unsigned short* Vb = vT_ws + (size_t)bh * 64 * SEQ;
  unsigned short* Pw = &P[w][0];

  short8 qf0 = *(const short8*)&Qb[(size_t)(qw + qi) * 64 + g * 8];
  short8 qf1 = *(const short8*)&Qb[(size_t)(qw + qi) * 64 + g * 8 + 32];

  f32x4 oacc[4] = {};
  float m_run = -3.0e38f, l_run = 0.f;
  int nkb = qw / 32 + 1;

  for (int kb = 0; kb < nkb; ++kb) {
    int k0 = kb * 32;
    // K fragments (A-operand of S^T = K·Q^T), direct from global
    short8 kf00 = *(const short8*)&Kb[(size_t)(k0 + qi) * 64 + g * 8];
    short8 kf01 = *(const short8*)&Kb[(size_t)(k0 + qi) * 64 + g * 8 + 32];
    short8 kf10 = *(const short8*)&Kb[(size_t)(k0 + 16 + qi) * 64 + g * 8];
    short8 kf11 = *(const short8*)&Kb[(size_t)(k0 + 16 + qi) * 64 + g * 8 + 32];
    // V^T fragments (A-operand of O^T = V^T·P^T), direct from global
    short8 vf[4];
    #pragma unroll
    for (int dt = 0; dt < 4; ++dt)
      vf[dt] = *(const short8*)&Vb[(size_t)(dt * 16 + qi) * SEQ + k0 + g * 8];

    f32x4 z = {};
    f32x4 s0 = __builtin_amdgcn_mfma_f32_16x16x32_bf16(kf00, qf0, z, 0, 0, 0);
    s0 = __builtin_amdgcn_mfma_f32_16x16x32_bf16(kf01, qf1, s0, 0, 0, 0);
    f32x4 s1 = __builtin_amdgcn_mfma_f32_16x16x32_bf16(kf10, qf0, z, 0, 0, 0);
    s1 = __builtin_amdgcn_mfma_f32_16x16x32_bf16(kf11, qf1, s1, 0, 0, 0);

    // online softmax; lane (g,qi) holds keys {k0+st*16+g*4+r} for q-row qrow
    float s[8];
    float tmax = -3.0e38f;
    #pragma unroll
    for (int r = 0; r < 4; ++r) {
      int key0 = k0 + g * 4 + r;
      float v0 = (key0 <= qrow) ? s0[r] * 0.125f : -3.0e38f;
      int key1 = key0 + 16;
      float v1 = (key1 <= qrow) ? s1[r] * 0.125f : -3.0e38f;
      s[r] = v0; s[4 + r] = v1;
      tmax = fmaxf(tmax, fmaxf(v0, v1));
    }
    tmax = fmaxf(tmax, __shfl_xor(tmax, 16, 64));
    tmax = fmaxf(tmax, __shfl_xor(tmax, 32, 64));
    float m_new = fmaxf(m_run, tmax);
    float alpha = __expf(m_run - m_new);
    float psum = 0.f;
    unsigned short pb[8];
    #pragma unroll
    for (int i = 0; i < 8; ++i) {
      float p = __expf(s[i] - m_new);   // masked -> exp(-huge) = 0
      psum += p;
      pb[i] = f2bf(p);
    }
    psum += __shfl_xor(psum, 16, 64);
    psum += __shfl_xor(psum, 32, 64);
    l_run = l_run * alpha + psum;
    m_run = m_new;

    // P^T staging: lane writes row q=qi, cols st*16+g*4..+3 (2x b32 each)
    #pragma unroll
    for (int st = 0; st < 2; ++st) {
      uint32_t lo = (uint32_t)pb[st * 4 + 0] | ((uint32_t)pb[st * 4 + 1] << 16);
      uint32_t hi = (uint32_t)pb[st * 4 + 2] | ((uint32_t)pb[st * 4 + 3] << 16);
      *(uint32_t*)&Pw[qi * 36 + st * 16 + g * 4] = lo;
      *(uint32_t*)&Pw[qi * 36 + st * 16 + g * 4 + 2] = hi;
    }
    short8 pB = *(const short8*)&Pw[qi * 36 + g * 8];  // B-frag: P[qi][g*8..]

    #pragma unroll
    for (int dt = 0; dt < 4; ++dt) {
      f32x4 t = oacc[dt];
      #pragma unroll
      for (int r = 0; r < 4; ++r) t[r] *= alpha;       // alpha is per-lane (col q = qi)
      oacc[dt] = __builtin_amdgcn_mfma_f32_16x16x32_bf16(vf[dt], pB, t, 0, 0, 0);
    }
  }

  float inv = 1.0f / l_run;   // l_run is this lane's own q-row denom
  int b = bh >> 4, h = bh & 15;
  size_t rowbase = ((size_t)(b * SEQ + qw + qi)) * 1024 + h * 64;
  #pragma unroll
  for (int dt = 0; dt < 4; ++dt) {
    ushort4 o;
    o.x = f2bf(oacc[dt][0] * inv);
    o.y = f2bf(oacc[dt][1] * inv);
    o.z = f2bf(oacc[dt][2] * inv);
    o.w = f2bf(oacc[dt][3] * inv);
    *(ushort4*)&a_out[rowbase + dt * 16 + g * 4] = o;
  }
}

// ---------------- launch ----------------
extern "C" void kernel_launch(void* const* d_in, const int* in_sizes, int n_in,
                              void* d_out, int out_size, void* d_ws, size_t ws_size,
                              hipStream_t stream) {
  const float* x      = (const float*)d_in[0];
  const float* w_attn = (const float*)d_in[1];
  const float* b_attn = (const float*)d_in[2];
  const float* w_proj = (const float*)d_in[3];
  const float* b_proj = (const float*)d_in[4];
  float* out = (float*)d_out;
  char* ws = (char*)d_ws;
  // ws layout (48 MB total)
  unsigned short* x_bf  = (unsigned short*)(ws);               //  8 MB
  unsigned short* waT   = (unsigned short*)(ws + 8388608);     //  6 MB
  unsigned short* wpT   = (unsigned short*)(ws + 14680064);    //  2 MB
  unsigned short* q_ws  = (unsigned short*)(ws + 16777216);    //  8 MB
  unsigned short* k_ws  = (unsigned short*)(ws + 25165824);    //  8 MB
  unsigned short* vT_ws = (unsigned short*)(ws + 33554432);    //  8 MB
  unsigned short* a_ws  = (unsigned short*)(ws + 41943040);    //  8 MB

  hipLaunchKernelGGL(k_cvt, dim3(4096), dim3(256), 0, stream, x, x_bf, 4194304 / 4);
  hipLaunchKernelGGL(k_tcvt, dim3(48, 16), dim3(256), 0, stream, w_attn, waT, 1024, 3072);
  hipLaunchKernelGGL(k_tcvt, dim3(16, 16), dim3(256), 0, stream, w_proj, wpT, 1024, 1024);
  hipLaunchKernelGGL(k_gemm_qkv, dim3(768), dim3(256), 0, stream,
                     x_bf, waT, b_attn, out, q_ws, k_ws, vT_ws);
  hipLaunchKernelGGL(k_attn, dim3(1024), dim3(256), 0, stream, q_ws, k_ws, vT_ws, a_ws);
  hipLaunchKernelGGL(k_gemm_proj, dim3(256), dim3(256), 0, stream, a_ws, wpT, b_proj, out);
}